// Round 1
// baseline (872.097 us; speedup 1.0000x reference)
//
#include <hip/hip_runtime.h>
#include <hip/hip_bf16.h>

// StabilityPredictorSchnet: B=4, L=384, H=128, F=384
// One block per (b,l). 6 k-tiles of 64 edge rows:
//   DMA h_E fp32 tile -> LDS (global_load_lds w=16, staged in sT1 region)
//   repack -> sA bf16 (padded)
//   GEMM1: sA[64x128] @ fw1 -> gelu -> sT1 (bf16)   [mfma 16x16x32 bf16]
//   GEMM2: sT1[64x384] @ fw2 -> gelu -> * h_V -> xc (register accum)
// Head MLP + last-block finalize fused in.
// R3 lesson: register-held cross-GEMM prefetch -> spills. Use global_load_lds.
// R5 (this round): latency-bound at 2 waves/SIMD. (a) 512-thread blocks,
// __launch_bounds__(512,4): same 71KB LDS, 2 blk/CU -> 4 waves/SIMD.
// (b) SWAPPED mfma operands (fragments are layout-symmetric): acc holds
// C^T so lane owns 4 consecutive n at fixed m -> epi1 = 12 ds_write_b64
// (was 96 b16), epi2 h_V = 12 float4 loads (was 96 scalar), float4 biases.

#define Bz 4
#define Lz 384
#define Hz 128
#define Fz 384
#define KT 64          // k-tile rows (edge rows per iteration)
#define NIT 6          // 384 / KT

typedef short bf16x8 __attribute__((ext_vector_type(8)));
typedef float f32x4 __attribute__((ext_vector_type(4)));

__device__ __forceinline__ unsigned short f2bf(float f) {
  unsigned int u = __float_as_uint(f);
  u += 0x7FFFu + ((u >> 16) & 1u);   // RNE bf16
  return (unsigned short)(u >> 16);
}

// gelu(x) = 0.5x(1+erf(x/sqrt2)); erf via A&S 7.1.26 (|err|<=1.5e-7)
__device__ __forceinline__ float gelu_f(float x) {
  const float a1 = 0.254829592f, a2 = -0.284496736f, a3 = 1.421413741f;
  const float a4 = -1.453152027f, a5 = 1.061405429f;
  float z = fabsf(x) * 0.7071067811865476f;
  float t = __builtin_amdgcn_rcpf(__builtin_fmaf(0.3275911f, z, 1.0f));
  float poly = t * (a1 + t * (a2 + t * (a3 + t * (a4 + t * a5))));
  float e = __builtin_fmaf(-poly, __expf(-z * z), 1.0f);
  return 0.5f * x * (1.0f + copysignf(e, x));
}

// ---- prep: zero acc/counter; pack fw1/fw2 into MFMA B-fragment order ----
// fw1P flat: ((t*4+ks)*64+lane)*8+j  = bf(fw1[(ks*32+(lane>>4)*8+j)*F + t*16+(lane&15)])
// fw2P flat: ((t*12+ks)*64+lane)*8+j = bf(fw2[...same...])
__global__ __launch_bounds__(256) void prep_kernel(
    const float* __restrict__ fw1, const float* __restrict__ fw2,
    unsigned short* __restrict__ fw1P, unsigned short* __restrict__ fw2P,
    float* __restrict__ accbuf, int* __restrict__ ctr)
{
  int e = blockIdx.x * 256 + threadIdx.x;
  if (e < 16) accbuf[e] = 0.0f;
  if (e == 16) *ctr = 0;
  if (e < 24 * 4 * 64 * 8) {
    int j = e & 7, lf = (e >> 3) & 63, ks = (e >> 9) & 3, t = e >> 11;
    int n = t * 16 + (lf & 15);
    int k = ks * 32 + (lf >> 4) * 8 + j;
    fw1P[e] = f2bf(fw1[(size_t)k * Fz + n]);
  } else if (e < 24 * 4 * 64 * 8 + 24 * 12 * 64 * 8) {
    int o = e - 24 * 4 * 64 * 8;
    int j = o & 7, lf = (o >> 3) & 63, r = o >> 9;
    int ks = r % 12, t = r / 12;
    int n = t * 16 + (lf & 15);
    int k = ks * 32 + (lf >> 4) * 8 + j;
    fw2P[o] = f2bf(fw2[(size_t)k * Fz + n]);
  }
}

__global__ __launch_bounds__(512, 4) void schnet_main(
    const float* __restrict__ hV, const float* __restrict__ hE,
    const float* __restrict__ mask,
    const unsigned short* __restrict__ fw1P, const float* __restrict__ fb1,
    const unsigned short* __restrict__ fw2P, const float* __restrict__ fb2,
    const float* __restrict__ hw1, const float* __restrict__ hb1,
    const float* __restrict__ hw2, const float* __restrict__ hb2,
    const float* __restrict__ hw3, const float* __restrict__ hb3,
    float* __restrict__ accbuf, int* __restrict__ ctr,
    float* __restrict__ out)
{
  const int bl   = blockIdx.x;
  const int b    = bl / Lz;
  const int l    = bl - b * Lz;
  const int tid  = threadIdx.x;
  const int wave = tid >> 6;    // 0..7
  const int lane = tid & 63;
  const int lr   = lane & 15;   // 16-index
  const int quad = lane >> 4;   // 0..3

  // sT1 region doubles as the fp32 staging buffer (32 KB <= 50 KB).
  __shared__ unsigned short sT1[KT][392];  // 50176 B
  __shared__ unsigned short sA[KT][136];   // 17408 B, padded bf16 tile
  __shared__ float sXC[Fz];
  __shared__ float sHp[4][Hz];
  __shared__ float sH1[Hz];
  __shared__ float sH2[64];
  __shared__ int   sLast;

  float* sStage = (float*)&sT1[0][0];

  const float* hE_bl = hE + (size_t)bl * (Lz * Hz);
  const unsigned short* w1base = fw1P + (size_t)lane * 8;
  const unsigned short* w2base = fw2P + (size_t)lane * 8;

  const f32x4 zero4 = {0.f, 0.f, 0.f, 0.f};
  f32x4 xc[3];
  xc[0] = zero4; xc[1] = zero4; xc[2] = zero4;

  for (int it = 0; it < NIT; ++it) {
    // (a) prev iter done with sA (GEMM1) and sT1 (GEMM2)
    __syncthreads();

    // ---- DMA 64x128 fp32 tile -> sStage (wave-uniform base + lane*16) ----
    {
      const char* gt = (const char*)(hE_bl + (size_t)it * (KT * Hz));
      #pragma unroll
      for (int j = 0; j < 4; ++j) {
        int chunk = (j * 8 + wave) * 1024;      // bytes
        __builtin_amdgcn_global_load_lds(
            (const __attribute__((address_space(1))) void*)(gt + chunk + lane * 16),
            (__attribute__((address_space(3))) void*)((char*)sStage + chunk),
            16, 0, 0);
      }
    }
    // (b) DMA complete
    __syncthreads();

    // ---- repack fp32 stage -> bf16 sA (conflict-free both sides) ----
    #pragma unroll
    for (int s = 0; s < 4; ++s) {
      int f = 4 * tid + 2048 * s;
      float4 v = *(const float4*)(sStage + f);
      int row = f >> 7, col = f & 127;
      short4 o;
      o.x = (short)f2bf(v.x); o.y = (short)f2bf(v.y);
      o.z = (short)f2bf(v.z); o.w = (short)f2bf(v.w);
      *(short4*)&sA[row][col] = o;
    }
    // (c) sA ready; sStage region free for epi1 output
    __syncthreads();

    // ===== GEMM1 (swapped): acc = (sA @ fw1)^T chunk; wave owns 48 cols ====
    // acc[mt][nt][r] = T1[m][n], m = mt*16+lr, n = wave*48+nt*16+quad*4+r
    {
      f32x4 acc[4][3];
      #pragma unroll
      for (int mt = 0; mt < 4; ++mt)
        #pragma unroll
        for (int nt = 0; nt < 3; ++nt) acc[mt][nt] = zero4;

      #pragma unroll 2
      for (int ks = 0; ks < 4; ++ks) {
        const int k0 = ks * 32 + quad * 8;
        bf16x8 afr[4];
        #pragma unroll
        for (int mt = 0; mt < 4; ++mt)
          afr[mt] = *(const bf16x8*)(&sA[mt * 16 + lr][k0]);
        bf16x8 bfr[3];
        #pragma unroll
        for (int nt = 0; nt < 3; ++nt)
          bfr[nt] = *(const bf16x8*)(w1base +
                        (size_t)(((wave * 3 + nt) * 4 + ks) * 64) * 8);
        #pragma unroll
        for (int mt = 0; mt < 4; ++mt)
          #pragma unroll
          for (int nt = 0; nt < 3; ++nt)
            acc[mt][nt] = __builtin_amdgcn_mfma_f32_16x16x32_bf16(
                bfr[nt], afr[mt], acc[mt][nt], 0, 0, 0);   // SWAPPED -> C^T
      }
      // epi1: bias+gelu -> sT1, packed b64 (4 consecutive n per lane)
      #pragma unroll
      for (int nt = 0; nt < 3; ++nt) {
        const int n0 = wave * 48 + nt * 16 + quad * 4;
        const f32x4 bias = *(const f32x4*)(fb1 + n0);
        #pragma unroll
        for (int mt = 0; mt < 4; ++mt) {
          short4 o;
          o.x = (short)f2bf(gelu_f(acc[mt][nt][0] + bias[0]));
          o.y = (short)f2bf(gelu_f(acc[mt][nt][1] + bias[1]));
          o.z = (short)f2bf(gelu_f(acc[mt][nt][2] + bias[2]));
          o.w = (short)f2bf(gelu_f(acc[mt][nt][3] + bias[3]));
          *(short4*)&sT1[mt * 16 + lr][n0] = o;
        }
      }
    }
    // (d) sT1 ready
    __syncthreads();

    // ===== GEMM2 (swapped): acc = (sT1 @ fw2)^T chunk =====
    {
      f32x4 acc[4][3];
      #pragma unroll
      for (int mt = 0; mt < 4; ++mt)
        #pragma unroll
        for (int nt = 0; nt < 3; ++nt) acc[mt][nt] = zero4;

      #pragma unroll 2
      for (int ks = 0; ks < 12; ++ks) {
        const int k0 = ks * 32 + quad * 8;
        bf16x8 afr[4];
        #pragma unroll
        for (int mt = 0; mt < 4; ++mt)
          afr[mt] = *(const bf16x8*)(&sT1[mt * 16 + lr][k0]);
        bf16x8 bfr[3];
        #pragma unroll
        for (int nt = 0; nt < 3; ++nt)
          bfr[nt] = *(const bf16x8*)(w2base +
                        (size_t)(((wave * 3 + nt) * 12 + ks) * 64) * 8);
        #pragma unroll
        for (int mt = 0; mt < 4; ++mt)
          #pragma unroll
          for (int nt = 0; nt < 3; ++nt)
            acc[mt][nt] = __builtin_amdgcn_mfma_f32_16x16x32_bf16(
                bfr[nt], afr[mt], acc[mt][nt], 0, 0, 0);   // SWAPPED -> C^T
      }
      // epi2: bias+gelu, * h_V[b, k=m, n] (float4), accumulate per n
      #pragma unroll
      for (int nt = 0; nt < 3; ++nt) {
        const int n0 = wave * 48 + nt * 16 + quad * 4;
        const f32x4 b2 = *(const f32x4*)(fb2 + n0);
        #pragma unroll
        for (int mt = 0; mt < 4; ++mt) {
          const float* hv =
              hV + ((size_t)b * Lz + it * KT + mt * 16 + lr) * Fz + n0;
          const f32x4 hvv = *(const f32x4*)hv;
          #pragma unroll
          for (int r = 0; r < 4; ++r)
            xc[nt][r] += gelu_f(acc[mt][nt][r] + b2[r]) * hvv[r];
        }
      }
    }
  }

  // reduce xc across the 16 lr lanes (rows m = lr mod 16) -> sXC[n]
  #pragma unroll
  for (int nt = 0; nt < 3; ++nt)
    #pragma unroll
    for (int r = 0; r < 4; ++r) {
      float v = xc[nt][r];
      v += __shfl_xor(v, 1);
      v += __shfl_xor(v, 2);
      v += __shfl_xor(v, 4);
      v += __shfl_xor(v, 8);
      if (lr == 0) sXC[wave * 48 + nt * 16 + quad * 4 + r] = v;
    }
  __syncthreads();

  // ---- head MLP (fp32, tiny) ----
  {
    int i = tid & 127;
    int part = tid >> 7;              // 0..3
    float a = 0.f;
    const int f0 = part * 96;
    for (int f = f0; f < f0 + 96; ++f) a += sXC[f] * hw1[f * Hz + i];
    sHp[part][i] = a;
  }
  __syncthreads();
  if (tid < Hz)
    sH1[tid] = gelu_f(sHp[0][tid] + sHp[1][tid] + sHp[2][tid] + sHp[3][tid]
                      + hb1[tid]);
  __syncthreads();
  if (tid < 64) {
    float a = hb2[tid];
    for (int i = 0; i < Hz; ++i) a += sH1[i] * hw2[i * 64 + tid];
    sH2[tid] = gelu_f(a);
  }
  __syncthreads();
  if (wave == 0) {
    float v = sH2[lane] * hw3[lane];
    #pragma unroll
    for (int off = 32; off >= 1; off >>= 1) v += __shfl_xor(v, off);
    if (lane == 0) {
      float pred = v + hb3[0];
      atomicAdd(&accbuf[b], pred * mask[b * Lz + l]);
      __threadfence();
      sLast = (atomicAdd(ctr, 1) == (Bz * Lz - 1));
    }
  }
  __syncthreads();

  // ---- last block: finalize all 4 batches ----
  if (sLast && wave < Bz) {
    float s = 0.f;
    #pragma unroll
    for (int k = 0; k < Lz / 64; ++k) s += mask[wave * Lz + k * 64 + lane];
    #pragma unroll
    for (int off = 32; off >= 1; off >>= 1) s += __shfl_xor(s, off);
    if (lane == 0) {
      float vl = s < 1.0f ? 1.0f : s;
      float a = atomicAdd(&accbuf[wave], 0.0f);   // coherent read
      out[wave] = a / sqrtf(vl);
    }
  }
}

extern "C" void kernel_launch(void* const* d_in, const int* in_sizes, int n_in,
                              void* d_out, int out_size, void* d_ws, size_t ws_size,
                              hipStream_t stream)
{
  const float* hV   = (const float*)d_in[0];
  const float* hE   = (const float*)d_in[1];
  const float* mask = (const float*)d_in[2];
  const float* fw1  = (const float*)d_in[3];
  const float* fb1  = (const float*)d_in[4];
  const float* fw2  = (const float*)d_in[5];
  const float* fb2  = (const float*)d_in[6];
  const float* hw1  = (const float*)d_in[7];
  const float* hb1  = (const float*)d_in[8];
  const float* hw2  = (const float*)d_in[9];
  const float* hb2  = (const float*)d_in[10];
  const float* hw3  = (const float*)d_in[11];
  const float* hb3  = (const float*)d_in[12];
  float* out = (float*)d_out;

  // ws: [0,64) accbuf; [64,68) ctr; fw1P @1024 (96 KB); fw2P after (288 KB)
  float* accbuf = (float*)d_ws;
  int*   ctr    = (int*)((char*)d_ws + 64);
  unsigned short* fw1P = (unsigned short*)((char*)d_ws + 1024);
  unsigned short* fw2P = fw1P + 24 * 4 * 64 * 8;

  prep_kernel<<<768, 256, 0, stream>>>(fw1, fw2, fw1P, fw2P, accbuf, ctr);
  schnet_main<<<Bz * Lz, 512, 0, stream>>>(hV, hE, mask, fw1P, fb1, fw2P, fb2,
                                           hw1, hb1, hw2, hb2, hw3, hb3,
                                           accbuf, ctr, out);
}